// Round 27
// baseline (90.063 us; speedup 1.0000x reference)
//
#include <hip/hip_runtime.h>

#define HH 128
#define WW 128
#define BB 4
#define CC 64
#define CHN 21
#define NPIX (HH*WW)     // 16384
#define NTAP 24
#define PAD 4
#define PW 136
#define PH 136
#define PPLANE (PW*PH)   // 18496
#define PWQ (PW/4)       // 34
#define AGR 4            // affinity channel groups
#define ACH (CC/AGR)     // 16 channels per thread

typedef _Float16 h2 __attribute__((ext_vector_type(2)));
typedef _Float16 h4 __attribute__((ext_vector_type(4)));
typedef _Float16 h8 __attribute__((ext_vector_type(8)));

// 7 distinct displacements; tap k = (RDY[TIY[k]], RDY[TIX[k]]), reference order.
constexpr int RDY[7] = {-4, -2, -1, 0, 1, 2, 4};
constexpr int TIY[NTAP] = {2,2,2,3,3,4,4,4, 1,1,1,3,3,5,5,5, 0,0,0,3,3,6,6,6};
constexpr int TIX[NTAP] = {2,3,4,2,4,2,3,4, 1,3,5,1,5,1,3,5, 0,3,6,0,6,0,3,6};
// Affinity pair-kernel row/col tables (rb column units, 0 == w0-4).
constexpr int KR[NTAP] = {2,2,2,3,3,4,4,4, 1,1,1,3,3,5,5,5, 0,0,0,3,3,6,6,6};
constexpr int KC[NTAP] = {3,4,5,3,5,3,4,5, 2,4,6,2,6,2,4,6, 0,4,8,0,8,0,4,8};

__device__ __forceinline__ int clampi(int v, int lo, int hi) {
    return v < lo ? lo : (v > hi ? hi : v);
}

// ---- pad feats: edge-replicate [B,C,128,128] f32 -> [B,C,136,136] fp16 -----
__global__ __launch_bounds__(256) void pad_feats_kernel(
    const float* __restrict__ feats, _Float16* __restrict__ pfeats) {
    int t = blockIdx.x * blockDim.x + threadIdx.x;
    const int total = BB * CC * PH * PWQ;
    if (t >= total) return;
    int q = t % PWQ;
    int rest = t / PWQ;
    int ph = rest % PH;
    int pl = rest / PH;
    const float* sp = feats + (size_t)pl * NPIX + (size_t)clampi(ph - PAD, 0, HH - 1) * WW;
    h4 v;
    v[0] = (_Float16)sp[clampi(q * 4 + 0 - PAD, 0, WW - 1)];
    v[1] = (_Float16)sp[clampi(q * 4 + 1 - PAD, 0, WW - 1)];
    v[2] = (_Float16)sp[clampi(q * 4 + 2 - PAD, 0, WW - 1)];
    v[3] = (_Float16)sp[clampi(q * 4 + 3 - PAD, 0, WW - 1)];
    *((h4*)(pfeats + (size_t)pl * PPLANE + (size_t)ph * PW + q * 4)) = v;
}

// ---- fused affinity + mask-pack (R17/R22 best-measured version) ------------
// block = one row (128 px), 256 thr; thread = 2px x 16ch (4 channel groups).
// aff: [b][3][NPIX] h8.  m0: [b][3][NPIX] h8 (compact mask channel-groups).
__global__ __launch_bounds__(256) void affinity_kernel(
    const _Float16* __restrict__ pfeats, const float* __restrict__ mask,
    h8* __restrict__ aff, h8* __restrict__ m0) {
    __shared__ float red[AGR][NTAP][128];

    int t = threadIdx.x;
    int cg = t >> 6;                 // 0..3
    int pr = t & 63;                 // pair 0..63
    int w0 = pr * 2;
    int h  = blockIdx.x & 127;
    int b  = blockIdx.x >> 7;

    // ---- mask pack: t<128 writes 3 h8 planes at this row
    if (t < 128) {
        int px = t;
        const float* mp = mask + (size_t)b * CHN * NPIX + (size_t)h * WW + px;
        h8 o0, o1, o2;
        #pragma unroll
        for (int c = 0; c < 8; ++c)  o0[c] = (_Float16)mp[(size_t)c * NPIX];
        #pragma unroll
        for (int c = 0; c < 8; ++c)  o1[c] = (_Float16)mp[(size_t)(c + 8) * NPIX];
        #pragma unroll
        for (int c = 0; c < 5; ++c)  o2[c] = (_Float16)mp[(size_t)(c + 16) * NPIX];
        o2[5] = (_Float16)0.f; o2[6] = (_Float16)0.f; o2[7] = (_Float16)0.f;
        h8* md = m0 + (size_t)b * 3 * NPIX + h * WW + px;
        md[0]        = o0;
        md[NPIX]     = o1;
        md[2 * NPIX] = o2;
    }

    // ---- pair affinity accumulation
    const _Float16* fb = pfeats + (size_t)(b * CC + cg * ACH) * PPLANE
                       + (size_t)(h + PAD) * PW + w0;

    float acc[48];
    #pragma unroll
    for (int k = 0; k < 48; ++k) acc[k] = 0.f;

    for (int c = 0; c < ACH; ++c) {
        const _Float16* base = fb + (size_t)c * PPLANE;
        h2 rb[7][5];
        #pragma unroll
        for (int r = 0; r < 7; ++r) {
            const h2* rp = (const h2*)(base + RDY[r] * PW);
            #pragma unroll
            for (int i = 0; i < 5; ++i) rb[r][i] = rp[i];
        }
        float q0 = (float)rb[3][2][0];
        float q1 = (float)rb[3][2][1];
        float sum0 = 3.f * q0, ss0 = 3.f * q0 * q0;
        float sum1 = 3.f * q1, ss1 = 3.f * q1 * q1;
        #pragma unroll
        for (int k = 0; k < NTAP; ++k) {
            float x0 = (float)rb[KR[k]][KC[k] >> 1][KC[k] & 1];
            float x1 = (float)rb[KR[k]][(KC[k]+1) >> 1][(KC[k]+1) & 1];
            sum0 += x0; ss0 = fmaf(x0, x0, ss0);
            sum1 += x1; ss1 = fmaf(x1, x1, ss1);
        }
        float var0 = (ss0 - sum0 * sum0 * (1.f/27.f)) * (1.f/26.f);
        float var1 = (ss1 - sum1 * sum1 * (1.f/27.f)) * (1.f/26.f);
        float inv0 = 1.f / (1e-8f + 0.1f * sqrtf(fmaxf(var0, 0.f)));
        float inv1 = 1.f / (1e-8f + 0.1f * sqrtf(fmaxf(var1, 0.f)));
        #pragma unroll
        for (int k = 0; k < NTAP; ++k) {
            float x0 = (float)rb[KR[k]][KC[k] >> 1][KC[k] & 1];
            float x1 = (float)rb[KR[k]][(KC[k]+1) >> 1][(KC[k]+1) & 1];
            acc[2*k]   = fmaf(fabsf(x0 - q0), inv0, acc[2*k]);
            acc[2*k+1] = fmaf(fabsf(x1 - q1), inv1, acc[2*k+1]);
        }
    }

    #pragma unroll
    for (int k = 0; k < NTAP; ++k)
        *((float2*)&red[cg][k][w0]) = make_float2(acc[2*k], acc[2*k+1]);
    __syncthreads();

    if (t < 128) {
        int px = t;
        float s[NTAP];
        #pragma unroll
        for (int k = 0; k < NTAP; ++k)
            s[k] = (red[0][k][px] + red[1][k][px]) + (red[2][k][px] + red[3][k][px]);
        float mn = s[0];
        #pragma unroll
        for (int k = 1; k < NTAP; ++k) mn = fminf(mn, s[k]);
        float ev[NTAP];
        float tot = 0.f;
        #pragma unroll
        for (int k = 0; k < NTAP; ++k) {
            ev[k] = __expf((mn - s[k]) * (1.f/CC));
            tot += ev[k];
        }
        float ivt = 1.f / tot;
        int pix = h * WW + px;
        #pragma unroll
        for (int j = 0; j < 3; ++j) {
            h8 q;
            #pragma unroll
            for (int i = 0; i < 8; ++i) q[i] = (_Float16)(ev[8*j + i] * ivt);
            aff[((size_t)b * 3 + j) * NPIX + pix] = q;
        }
    }
}

// ---- propN: NIT fused iterations in LDS; PACKED fp16 math; tile param TS ---
template<int NIT, int TS, bool FIN>
__global__ __launch_bounds__(256, 4) void propN_kernel(
    const h8* __restrict__ src, const h8* __restrict__ aff,
    h8* __restrict__ dsth, float* __restrict__ dstf) {
    constexpr int S0 = TS + 8 * NIT;
    constexpr int S1 = S0 - 8;
    constexpr int NTILE = 128 / TS;
    __shared__ __align__(16) _Float16 ldsraw[(S0*(S0+1) + S1*(S1+1)) * 8];
    h8* bufA = (h8*)ldsraw;
    h8* bufB = bufA + S0 * (S0 + 1);

    int tid = threadIdx.x;
    int tx = (blockIdx.x % NTILE) * TS;
    int ty = (blockIdx.x / NTILE) * TS;
    int cg = blockIdx.y;             // 0..2
    int b  = blockIdx.z;

    const h8* sp = src + ((size_t)b * 3 + cg) * NPIX;
    {
        const int Oy = ty - 4 * NIT, Ox = tx - 4 * NIT;
        for (int p = tid; p < S0 * S0; p += 256) {
            int y = p / S0, x = p - y * S0;
            int gh = clampi(Oy + y, 0, HH - 1);
            int gw = clampi(Ox + x, 0, WW - 1);
            bufA[y * (S0 + 1) + x] = sp[gh * WW + gw];
        }
    }
    __syncthreads();

    const h8* affb = aff + (size_t)b * 3 * NPIX;
    h8* pin = bufA;
    h8* pout = bufB;
    int Sin = S0, Oyin = ty - 4 * NIT, Oxin = tx - 4 * NIT;

    #pragma unroll
    for (int it = 1; it <= NIT; ++it) {
        const int Sc = Sin - 8;
        const int Oyc = Oyin + 4, Oxc = Oxin + 4;
        for (int p = tid; p < Sc * Sc; p += 256) {
            int y = p / Sc, x = p - y * Sc;
            int gh = clampi(Oyc + y, 0, HH - 1);
            int gw = clampi(Oxc + x, 0, WW - 1);
            int pix = gh * WW + gw;

            int ro[7], co[7];
            #pragma unroll
            for (int r = 0; r < 7; ++r) {
                ro[r] = (clampi(gh + RDY[r], 0, HH - 1) - Oyin) * (Sin + 1);
                co[r] = clampi(gw + RDY[r], 0, WW - 1) - Oxin;
            }

            h8 acc;
            #pragma unroll
            for (int i = 0; i < 8; ++i) acc[i] = (_Float16)0.f;
            #pragma unroll
            for (int j = 0; j < 3; ++j) {
                h8 q = affb[(size_t)j * NPIX + pix];
                #pragma unroll
                for (int kk = 0; kk < 8; ++kk) {
                    int k = j * 8 + kk;
                    h8 m = pin[ro[TIY[k]] + co[TIX[k]]];
                    _Float16 a = q[kk];
                    h8 av;
                    #pragma unroll
                    for (int i = 0; i < 8; ++i) av[i] = a;
                    acc = m * av + acc;
                }
            }

            if (it < NIT) {
                pout[y * (Sc + 1) + x] = acc;
            } else if (FIN) {
                float* ob = dstf + (size_t)b * CHN * NPIX + pix;
                #pragma unroll
                for (int i = 0; i < 8; ++i) {
                    int ch = cg * 8 + i;
                    if (ch < CHN) ob[(size_t)ch * NPIX] = (float)acc[i];
                }
            } else {
                dsth[((size_t)b * 3 + cg) * NPIX + pix] = acc;
            }
        }
        if (it < NIT) {
            __syncthreads();
            h8* tswap = pin; pin = pout; pout = tswap;
            Sin = Sc; Oyin = Oyc; Oxin = Oxc;
        }
    }
}

extern "C" void kernel_launch(void* const* d_in, const int* in_sizes, int n_in,
                              void* d_out, int out_size, void* d_ws, size_t ws_size,
                              hipStream_t stream) {
    const float* feats = (const float*)d_in[0];
    const float* mask  = (const float*)d_in[1];
    float* out = (float*)d_out;

    const size_t pfeatsE = (size_t)BB * CC * PPLANE;    // halfs
    const size_t affQ    = (size_t)BB * 3 * NPIX;       // h8 (16 B each)

    _Float16* pfeats = (_Float16*)d_ws;
    h8*       aff    = (h8*)(pfeats + pfeatsE);
    h8*       m0     = aff + affQ;
    h8*       m1     = m0 + affQ;

    {
        int total = BB * CC * PH * PWQ;
        pad_feats_kernel<<<dim3((total + 255) / 256), dim3(256), 0, stream>>>(feats, pfeats);
    }
    // affinity also packs mask -> m0
    affinity_kernel<<<dim3(BB * HH), dim3(256), 0, stream>>>(pfeats, mask, aff, m0);

    // 10 iterations = 5 x depth-2 at TS=8 (3072 blocks -> 16+ waves/CU)
    dim3 g2(256, 3, BB);
    propN_kernel<2, 8, false><<<g2, dim3(256), 0, stream>>>(m0, aff, m1, nullptr);
    propN_kernel<2, 8, false><<<g2, dim3(256), 0, stream>>>(m1, aff, m0, nullptr);
    propN_kernel<2, 8, false><<<g2, dim3(256), 0, stream>>>(m0, aff, m1, nullptr);
    propN_kernel<2, 8, false><<<g2, dim3(256), 0, stream>>>(m1, aff, m0, nullptr);
    propN_kernel<2, 8, true ><<<g2, dim3(256), 0, stream>>>(m0, aff, nullptr, out);
}

// Round 28
// 78.059 us; speedup vs baseline: 1.1538x; 1.1538x over previous
//
#include <hip/hip_runtime.h>

#define HH 128
#define WW 128
#define BB 4
#define CC 64
#define CHN 21
#define NPIX (HH*WW)     // 16384
#define NTAP 24
#define PAD 4
#define PW 136
#define PH 136
#define PPLANE (PW*PH)   // 18496
#define PWQ (PW/4)       // 34
#define AGR 4            // affinity channel groups
#define ACH (CC/AGR)     // 16 channels per thread

typedef _Float16 h2 __attribute__((ext_vector_type(2)));
typedef _Float16 h4 __attribute__((ext_vector_type(4)));
typedef _Float16 h8 __attribute__((ext_vector_type(8)));

// 7 distinct displacements; tap k = (RDY[TIY[k]], RDY[TIX[k]]), reference order.
constexpr int RDY[7] = {-4, -2, -1, 0, 1, 2, 4};
constexpr int TIY[NTAP] = {2,2,2,3,3,4,4,4, 1,1,1,3,3,5,5,5, 0,0,0,3,3,6,6,6};
constexpr int TIX[NTAP] = {2,3,4,2,4,2,3,4, 1,3,5,1,5,1,3,5, 0,3,6,0,6,0,3,6};
// Affinity pair-kernel row/col tables (rb column units, 0 == w0-4).
constexpr int KR[NTAP] = {2,2,2,3,3,4,4,4, 1,1,1,3,3,5,5,5, 0,0,0,3,3,6,6,6};
constexpr int KC[NTAP] = {3,4,5,3,5,3,4,5, 2,4,6,2,6,2,4,6, 0,4,8,0,8,0,4,8};

__device__ __forceinline__ int clampi(int v, int lo, int hi) {
    return v < lo ? lo : (v > hi ? hi : v);
}

// ---- pad feats: edge-replicate [B,C,128,128] f32 -> [B,C,136,136] fp16 -----
__global__ __launch_bounds__(256) void pad_feats_kernel(
    const float* __restrict__ feats, _Float16* __restrict__ pfeats) {
    int t = blockIdx.x * blockDim.x + threadIdx.x;
    const int total = BB * CC * PH * PWQ;
    if (t >= total) return;
    int q = t % PWQ;
    int rest = t / PWQ;
    int ph = rest % PH;
    int pl = rest / PH;
    const float* sp = feats + (size_t)pl * NPIX + (size_t)clampi(ph - PAD, 0, HH - 1) * WW;
    h4 v;
    v[0] = (_Float16)sp[clampi(q * 4 + 0 - PAD, 0, WW - 1)];
    v[1] = (_Float16)sp[clampi(q * 4 + 1 - PAD, 0, WW - 1)];
    v[2] = (_Float16)sp[clampi(q * 4 + 2 - PAD, 0, WW - 1)];
    v[3] = (_Float16)sp[clampi(q * 4 + 3 - PAD, 0, WW - 1)];
    *((h4*)(pfeats + (size_t)pl * PPLANE + (size_t)ph * PW + q * 4)) = v;
}

// ---- fused affinity + mask-pack (best-measured: R17/R22) -------------------
// block = one row (128 px), 256 thr; thread = 2px x 16ch (4 channel groups).
// aff: [b][3][NPIX] h8.  m0: [b][3][NPIX] h8 (compact mask channel-groups).
__global__ __launch_bounds__(256) void affinity_kernel(
    const _Float16* __restrict__ pfeats, const float* __restrict__ mask,
    h8* __restrict__ aff, h8* __restrict__ m0) {
    __shared__ float red[AGR][NTAP][128];

    int t = threadIdx.x;
    int cg = t >> 6;                 // 0..3
    int pr = t & 63;                 // pair 0..63
    int w0 = pr * 2;
    int h  = blockIdx.x & 127;
    int b  = blockIdx.x >> 7;

    // ---- mask pack: t<128 writes 3 h8 planes at this row
    if (t < 128) {
        int px = t;
        const float* mp = mask + (size_t)b * CHN * NPIX + (size_t)h * WW + px;
        h8 o0, o1, o2;
        #pragma unroll
        for (int c = 0; c < 8; ++c)  o0[c] = (_Float16)mp[(size_t)c * NPIX];
        #pragma unroll
        for (int c = 0; c < 8; ++c)  o1[c] = (_Float16)mp[(size_t)(c + 8) * NPIX];
        #pragma unroll
        for (int c = 0; c < 5; ++c)  o2[c] = (_Float16)mp[(size_t)(c + 16) * NPIX];
        o2[5] = (_Float16)0.f; o2[6] = (_Float16)0.f; o2[7] = (_Float16)0.f;
        h8* md = m0 + (size_t)b * 3 * NPIX + h * WW + px;
        md[0]        = o0;
        md[NPIX]     = o1;
        md[2 * NPIX] = o2;
    }

    // ---- pair affinity accumulation
    const _Float16* fb = pfeats + (size_t)(b * CC + cg * ACH) * PPLANE
                       + (size_t)(h + PAD) * PW + w0;

    float acc[48];
    #pragma unroll
    for (int k = 0; k < 48; ++k) acc[k] = 0.f;

    for (int c = 0; c < ACH; ++c) {
        const _Float16* base = fb + (size_t)c * PPLANE;
        h2 rb[7][5];
        #pragma unroll
        for (int r = 0; r < 7; ++r) {
            const h2* rp = (const h2*)(base + RDY[r] * PW);
            #pragma unroll
            for (int i = 0; i < 5; ++i) rb[r][i] = rp[i];
        }
        float q0 = (float)rb[3][2][0];
        float q1 = (float)rb[3][2][1];
        float sum0 = 3.f * q0, ss0 = 3.f * q0 * q0;
        float sum1 = 3.f * q1, ss1 = 3.f * q1 * q1;
        #pragma unroll
        for (int k = 0; k < NTAP; ++k) {
            float x0 = (float)rb[KR[k]][KC[k] >> 1][KC[k] & 1];
            float x1 = (float)rb[KR[k]][(KC[k]+1) >> 1][(KC[k]+1) & 1];
            sum0 += x0; ss0 = fmaf(x0, x0, ss0);
            sum1 += x1; ss1 = fmaf(x1, x1, ss1);
        }
        float var0 = (ss0 - sum0 * sum0 * (1.f/27.f)) * (1.f/26.f);
        float var1 = (ss1 - sum1 * sum1 * (1.f/27.f)) * (1.f/26.f);
        float inv0 = 1.f / (1e-8f + 0.1f * sqrtf(fmaxf(var0, 0.f)));
        float inv1 = 1.f / (1e-8f + 0.1f * sqrtf(fmaxf(var1, 0.f)));
        #pragma unroll
        for (int k = 0; k < NTAP; ++k) {
            float x0 = (float)rb[KR[k]][KC[k] >> 1][KC[k] & 1];
            float x1 = (float)rb[KR[k]][(KC[k]+1) >> 1][(KC[k]+1) & 1];
            acc[2*k]   = fmaf(fabsf(x0 - q0), inv0, acc[2*k]);
            acc[2*k+1] = fmaf(fabsf(x1 - q1), inv1, acc[2*k+1]);
        }
    }

    #pragma unroll
    for (int k = 0; k < NTAP; ++k)
        *((float2*)&red[cg][k][w0]) = make_float2(acc[2*k], acc[2*k+1]);
    __syncthreads();

    if (t < 128) {
        int px = t;
        float s[NTAP];
        #pragma unroll
        for (int k = 0; k < NTAP; ++k)
            s[k] = (red[0][k][px] + red[1][k][px]) + (red[2][k][px] + red[3][k][px]);
        float mn = s[0];
        #pragma unroll
        for (int k = 1; k < NTAP; ++k) mn = fminf(mn, s[k]);
        float ev[NTAP];
        float tot = 0.f;
        #pragma unroll
        for (int k = 0; k < NTAP; ++k) {
            ev[k] = __expf((mn - s[k]) * (1.f/CC));
            tot += ev[k];
        }
        float ivt = 1.f / tot;
        int pix = h * WW + px;
        #pragma unroll
        for (int j = 0; j < 3; ++j) {
            h8 q;
            #pragma unroll
            for (int i = 0; i < 8; ++i) q[i] = (_Float16)(ev[8*j + i] * ivt);
            aff[((size_t)b * 3 + j) * NPIX + pix] = q;
        }
    }
}

// ---- propN: 2 fused iterations in LDS; PACKED fp16 math (v_pk_fma_f16) -----
template<int NIT, bool FIN>
__global__ __launch_bounds__(256, 3) void propN_kernel(
    const h8* __restrict__ src, const h8* __restrict__ aff,
    h8* __restrict__ dsth, float* __restrict__ dstf) {
    constexpr int S0 = 16 + 8 * NIT;
    constexpr int S1 = S0 - 8;
    __shared__ __align__(16) _Float16 ldsraw[(S0*(S0+1) + S1*(S1+1)) * 8];
    h8* bufA = (h8*)ldsraw;
    h8* bufB = bufA + S0 * (S0 + 1);

    int tid = threadIdx.x;
    int tx = (blockIdx.x & 7) * 16;
    int ty = (blockIdx.x >> 3) * 16;
    int cg = blockIdx.y;             // 0..2
    int b  = blockIdx.z;

    const h8* sp = src + ((size_t)b * 3 + cg) * NPIX;
    {
        const int Oy = ty - 4 * NIT, Ox = tx - 4 * NIT;
        for (int p = tid; p < S0 * S0; p += 256) {
            int y = p / S0, x = p - y * S0;
            int gh = clampi(Oy + y, 0, HH - 1);
            int gw = clampi(Ox + x, 0, WW - 1);
            bufA[y * (S0 + 1) + x] = sp[gh * WW + gw];
        }
    }
    __syncthreads();

    const h8* affb = aff + (size_t)b * 3 * NPIX;
    h8* pin = bufA;
    h8* pout = bufB;
    int Sin = S0, Oyin = ty - 4 * NIT, Oxin = tx - 4 * NIT;

    #pragma unroll
    for (int it = 1; it <= NIT; ++it) {
        const int Sc = Sin - 8;
        const int Oyc = Oyin + 4, Oxc = Oxin + 4;
        for (int p = tid; p < Sc * Sc; p += 256) {
            int y = p / Sc, x = p - y * Sc;
            int gh = clampi(Oyc + y, 0, HH - 1);
            int gw = clampi(Oxc + x, 0, WW - 1);
            int pix = gh * WW + gw;

            int ro[7], co[7];
            #pragma unroll
            for (int r = 0; r < 7; ++r) {
                ro[r] = (clampi(gh + RDY[r], 0, HH - 1) - Oyin) * (Sin + 1);
                co[r] = clampi(gw + RDY[r], 0, WW - 1) - Oxin;
            }

            h8 acc;
            #pragma unroll
            for (int i = 0; i < 8; ++i) acc[i] = (_Float16)0.f;
            #pragma unroll
            for (int j = 0; j < 3; ++j) {
                h8 q = affb[(size_t)j * NPIX + pix];
                #pragma unroll
                for (int kk = 0; kk < 8; ++kk) {
                    int k = j * 8 + kk;
                    h8 m = pin[ro[TIY[k]] + co[TIX[k]]];
                    _Float16 a = q[kk];
                    h8 av;
                    #pragma unroll
                    for (int i = 0; i < 8; ++i) av[i] = a;
                    acc = m * av + acc;
                }
            }

            if (it < NIT) {
                pout[y * (Sc + 1) + x] = acc;
            } else if (FIN) {
                float* ob = dstf + (size_t)b * CHN * NPIX + pix;
                #pragma unroll
                for (int i = 0; i < 8; ++i) {
                    int ch = cg * 8 + i;
                    if (ch < CHN) ob[(size_t)ch * NPIX] = (float)acc[i];
                }
            } else {
                dsth[((size_t)b * 3 + cg) * NPIX + pix] = acc;
            }
        }
        if (it < NIT) {
            __syncthreads();
            h8* tswap = pin; pin = pout; pout = tswap;
            Sin = Sc; Oyin = Oyc; Oxin = Oxc;
        }
    }
}

extern "C" void kernel_launch(void* const* d_in, const int* in_sizes, int n_in,
                              void* d_out, int out_size, void* d_ws, size_t ws_size,
                              hipStream_t stream) {
    const float* feats = (const float*)d_in[0];
    const float* mask  = (const float*)d_in[1];
    float* out = (float*)d_out;

    const size_t pfeatsE = (size_t)BB * CC * PPLANE;    // halfs
    const size_t affQ    = (size_t)BB * 3 * NPIX;       // h8 (16 B each)

    _Float16* pfeats = (_Float16*)d_ws;
    h8*       aff    = (h8*)(pfeats + pfeatsE);
    h8*       m0     = aff + affQ;
    h8*       m1     = m0 + affQ;

    {
        int total = BB * CC * PH * PWQ;
        pad_feats_kernel<<<dim3((total + 255) / 256), dim3(256), 0, stream>>>(feats, pfeats);
    }
    // affinity also packs mask -> m0
    affinity_kernel<<<dim3(BB * HH), dim3(256), 0, stream>>>(pfeats, mask, aff, m0);

    // 10 iterations = 5 x depth-2; ping-pong m0/m1, last writes f32 out
    dim3 g2(64, 3, BB);
    propN_kernel<2, false><<<g2, dim3(256), 0, stream>>>(m0, aff, m1, nullptr);
    propN_kernel<2, false><<<g2, dim3(256), 0, stream>>>(m1, aff, m0, nullptr);
    propN_kernel<2, false><<<g2, dim3(256), 0, stream>>>(m0, aff, m1, nullptr);
    propN_kernel<2, false><<<g2, dim3(256), 0, stream>>>(m1, aff, m0, nullptr);
    propN_kernel<2, true ><<<g2, dim3(256), 0, stream>>>(m0, aff, nullptr, out);
}